// Round 11
// baseline (85.740 us; speedup 1.0000x reference)
//
#include <hip/hip_runtime.h>
#include <hip/hip_bf16.h>
#include <stdint.h>

#define NR 16384
#define KI 256
#define MO 128
#define ALPHA 0.01f
#define CH 32             // rows per chunk
#define NCH (NR / CH)     // 512 chunks
#define RB 8              // i-keys per thread in k_rank
#define JT 256            // j-keys staged in LDS per block
#define NJ (NR / JT)      // 64 j-chunks
#define NIR (NR / (256 * RB))   // 8 i-ranges

typedef unsigned long long u64;
typedef __attribute__((ext_vector_type(8))) short bf16x8;
typedef __attribute__((ext_vector_type(4))) float f32x4;

// sortable key: monotone float order, index tie-break (rank is a bijection)
static __device__ __forceinline__ u64 sort_key(float f, int j) {
    unsigned u = __float_as_uint(f);
    u ^= ((unsigned)((int)u >> 31)) | 0x80000000u;
    return (((u64)u) << 14) | (unsigned)(j & 0x3FFF);
}

static __device__ __forceinline__ ushort2 cvt2(float a, float b) {
    __hip_bfloat162 r = __float22bfloat162_rn(make_float2(a, b));
    return *reinterpret_cast<ushort2*>(&r);
}

// ---------------- K1: h = x@W^T via bf16 MFMA (R10-proven) + fused s1,s2,keys, rank=0, done=0 ----------------
__global__ __launch_bounds__(256) void k_gemm_fused(const float* __restrict__ x,
                                                    const float* __restrict__ w,
                                                    const float* __restrict__ a1,
                                                    const float* __restrict__ a2,
                                                    float* __restrict__ h,
                                                    float* __restrict__ s1,
                                                    float* __restrict__ s2,
                                                    u64* __restrict__ keys,
                                                    int* __restrict__ rank,
                                                    int* __restrict__ done) {
    __shared__ ushort Abf[64][40];
    __shared__ ushort Bbf[128][40];
    const int t = threadIdx.x;
    const int lane = t & 63;
    const int wv = t >> 6;
    const int rowBase = blockIdx.x * 64;
    const int xr = t >> 2, xc = (t & 3) << 3;
    const int wr = t >> 1, wc = (t & 1) << 4;
    const int fr = lane & 15;
    const int fk = (lane >> 4) << 3;

    if (blockIdx.x == 0 && t < NIR) done[t] = 0;   // re-zero finisher counters every call

    f32x4 acc[8] = {};

    float4 xv0 = *(const float4*)&x[(size_t)(rowBase + xr) * KI + xc];
    float4 xv1 = *(const float4*)&x[(size_t)(rowBase + xr) * KI + xc + 4];
    float4 wv0 = *(const float4*)&w[(size_t)wr * KI + wc];
    float4 wv1 = *(const float4*)&w[(size_t)wr * KI + wc + 4];
    float4 wv2 = *(const float4*)&w[(size_t)wr * KI + wc + 8];
    float4 wv3 = *(const float4*)&w[(size_t)wr * KI + wc + 12];

    for (int ks = 0; ks < KI / 32; ++ks) {
        __syncthreads();
        {
            union { ushort2 u2[4]; bf16x8 v; } ap;
            ap.u2[0] = cvt2(xv0.x, xv0.y); ap.u2[1] = cvt2(xv0.z, xv0.w);
            ap.u2[2] = cvt2(xv1.x, xv1.y); ap.u2[3] = cvt2(xv1.z, xv1.w);
            *(bf16x8*)&Abf[xr][xc] = ap.v;
            union { ushort2 u2[4]; bf16x8 v; } bp0, bp1;
            bp0.u2[0] = cvt2(wv0.x, wv0.y); bp0.u2[1] = cvt2(wv0.z, wv0.w);
            bp0.u2[2] = cvt2(wv1.x, wv1.y); bp0.u2[3] = cvt2(wv1.z, wv1.w);
            bp1.u2[0] = cvt2(wv2.x, wv2.y); bp1.u2[1] = cvt2(wv2.z, wv2.w);
            bp1.u2[2] = cvt2(wv3.x, wv3.y); bp1.u2[3] = cvt2(wv3.z, wv3.w);
            *(bf16x8*)&Bbf[wr][wc] = bp0.v;
            *(bf16x8*)&Bbf[wr][wc + 8] = bp1.v;
        }
        __syncthreads();
        if (ks + 1 < KI / 32) {
            int k0 = (ks + 1) * 32;
            xv0 = *(const float4*)&x[(size_t)(rowBase + xr) * KI + k0 + xc];
            xv1 = *(const float4*)&x[(size_t)(rowBase + xr) * KI + k0 + xc + 4];
            wv0 = *(const float4*)&w[(size_t)wr * KI + k0 + wc];
            wv1 = *(const float4*)&w[(size_t)wr * KI + k0 + wc + 4];
            wv2 = *(const float4*)&w[(size_t)wr * KI + k0 + wc + 8];
            wv3 = *(const float4*)&w[(size_t)wr * KI + k0 + wc + 12];
        }
        bf16x8 af = *(const bf16x8*)&Abf[wv * 16 + fr][fk];
#pragma unroll
        for (int n = 0; n < 8; ++n) {
            bf16x8 bfr = *(const bf16x8*)&Bbf[n * 16 + fr][fk];
            acc[n] = __builtin_amdgcn_mfma_f32_16x16x32_bf16(af, bfr, acc[n], 0, 0, 0);
        }
    }

    const int rq = lane >> 4;
#pragma unroll
    for (int n = 0; n < 8; ++n)
#pragma unroll
        for (int r = 0; r < 4; ++r)
            h[(size_t)(rowBase + wv * 16 + rq * 4 + r) * MO + n * 16 + fr] = acc[n][r];

    float a1v[8], a2v[8];
#pragma unroll
    for (int n = 0; n < 8; ++n) { a1v[n] = a1[n * 16 + fr]; a2v[n] = a2[n * 16 + fr]; }
#pragma unroll
    for (int r = 0; r < 4; ++r) {
        float p1 = 0.f, p2 = 0.f;
#pragma unroll
        for (int n = 0; n < 8; ++n) {
            p1 = fmaf(acc[n][r], a1v[n], p1);
            p2 = fmaf(acc[n][r], a2v[n], p2);
        }
#pragma unroll
        for (int off = 8; off; off >>= 1) {
            p1 += __shfl_xor(p1, off, 64);
            p2 += __shfl_xor(p2, off, 64);
        }
        if (fr == 0) {
            int row = rowBase + wv * 16 + rq * 4 + r;
            s1[row] = p1;
            s2[row] = p2;
            keys[row] = sort_key(p1, row);
            rank[row] = 0;
        }
    }
}

// ---------------- K2: rank counts + last-finisher scatter (scatter dispatch eliminated) ----------------
__global__ __launch_bounds__(256) void k_rank(const u64* __restrict__ keys,
                                              const float* __restrict__ s1,
                                              int* __restrict__ rank,
                                              int* __restrict__ done,
                                              float* __restrict__ s1s,
                                              int* __restrict__ perm) {
    __shared__ u64 sk[JT];
    __shared__ int lastFlag;
    const int t = threadIdx.x;
    const int ibase = blockIdx.x * (256 * RB);
    const int jbase = blockIdx.y * JT;
    if (t == 0) lastFlag = 0;
    sk[t] = keys[jbase + t];
    u64 ki[RB];
#pragma unroll
    for (int k = 0; k < RB; ++k) ki[k] = keys[ibase + k * 256 + t];
    int cnt[RB] = {};
    __syncthreads();
#pragma unroll 4
    for (int jj = 0; jj < JT; ++jj) {
        u64 kj = sk[jj];                 // uniform addr -> LDS broadcast, conflict-free
#pragma unroll
        for (int k = 0; k < RB; ++k)
            cnt[k] += (kj < ki[k]) ? 1 : 0;
    }
#pragma unroll
    for (int k = 0; k < RB; ++k)
        atomicAdd(&rank[ibase + k * 256 + t], cnt[k]);   // device-scope, deterministic sum

    // completion protocol: fence own atomics -> barrier -> one done-increment
    __threadfence();
    __syncthreads();
    if (t == 0) {
        if (atomicAdd(&done[blockIdx.x], 1) == NJ - 1) lastFlag = 1;
    }
    __syncthreads();
    if (lastFlag) {
        // all 64 j-slices for this i-range complete; ranks final. Scatter inline.
#pragma unroll
        for (int k = 0; k < RB; ++k) {
            int i = ibase + k * 256 + t;
            int r = atomicAdd(&rank[i], 0);   // coherent read of final rank
            s1s[r] = s1[i];
            perm[r] = i;
        }
    }
}

// ---------------- K3: within-chunk suffix + kidx searches on idle half-wave (R9-proven) ----------------
__global__ __launch_bounds__(256) void k_chunk(const float* __restrict__ h,
                                               const int* __restrict__ perm,
                                               const float* __restrict__ s1s,
                                               const float* __restrict__ s2,
                                               float2* __restrict__ SHSw,
                                               int* __restrict__ kidx) {
    __shared__ int pi[CH];
    __shared__ float ss[CH];
    __shared__ float rH[128], rS[128];
    const int t = threadIdx.x, c = t & 127, g = t >> 7, q = blockIdx.x;
    if (t < CH) { pi[t] = perm[q * CH + t]; ss[t] = s1s[q * CH + t]; }
    __syncthreads();
    float v[16];
#pragma unroll
    for (int m = 0; m < 16; ++m)
        v[m] = h[(size_t)pi[g * 16 + m] * MO + c];
    if (g == 1) {
        float runH = 0.f, runS = 0.f;
#pragma unroll
        for (int m = 15; m >= 0; --m) {
            runH += v[m];
            runS = fmaf(ss[16 + m], v[m], runS);
            SHSw[(size_t)(q * CH + 16 + m) * MO + c] = make_float2(runH, runS);
        }
        rH[c] = runH; rS[c] = runS;
    } else if (t < CH) {
        int i = q * CH + t;
        float tv = -s2[i];
        int lo = 0, hi = NR;
        while (lo < hi) {
            int mid = (lo + hi) >> 1;
            if (s1s[mid] < tv) lo = mid + 1; else hi = mid;
        }
        kidx[i] = lo;
    }
    __syncthreads();
    if (g == 0) {
        float runH = rH[c], runS = rS[c];
#pragma unroll
        for (int m = 15; m >= 0; --m) {
            runH += v[m];
            runS = fmaf(ss[m], v[m], runS);
            SHSw[(size_t)(q * CH + m) * MO + c] = make_float2(runH, runS);
        }
    }
    if (q == NCH - 1 && t < 128) SHSw[(size_t)NR * MO + t] = make_float2(0.f, 0.f);
}

// ---------------- K4: exclusive suffix over chunk sums (R9-proven) ----------------
__global__ __launch_bounds__(512) void k_scan(const float2* __restrict__ SHSw,
                                              float2* __restrict__ cSuf) {
    __shared__ float bufH[NCH], bufS[NCH];
    const int c = blockIdx.x, q = threadIdx.x;
    float2 hs = SHSw[(size_t)(q * CH) * MO + c];
    bufH[q] = hs.x; bufS[q] = hs.y;
    __syncthreads();
#pragma unroll
    for (int off = 1; off < NCH; off <<= 1) {
        float ah = 0.f, as = 0.f;
        if (q + off < NCH) { ah = bufH[q + off]; as = bufS[q + off]; }
        __syncthreads();
        bufH[q] += ah; bufS[q] += as;
        __syncthreads();
    }
    cSuf[q * MO + c] = make_float2(bufH[q] - hs.x, bufS[q] - hs.y);
    if (q == 0) cSuf[(size_t)NCH * MO + c] = make_float2(0.f, 0.f);
}

// ---------------- K5: out[i][c]; SH = SHSw[k]+cSuf[k>>5] (R9-proven) ----------------
__global__ __launch_bounds__(256) void k_final(const float2* __restrict__ SHSw,
                                               const float2* __restrict__ cSuf,
                                               const float* __restrict__ s2,
                                               const int* __restrict__ kidx,
                                               float* __restrict__ out) {
    int idx = blockIdx.x * 256 + threadIdx.x;
    int i = idx >> 7, c = idx & 127;
    float s2v = s2[i];
    int k = kidx[i];
    float2 w0 = SHSw[c];
    float2 c0 = cSuf[c];
    float2 wk = SHSw[(size_t)k * MO + c];
    float2 ck = cSuf[(size_t)(k >> 5) * MO + c];
    float th = w0.x + c0.x, tsh = w0.y + c0.y;
    float sh = wk.x + ck.x, sshv = wk.y + ck.y;
    out[idx] = ALPHA * fmaf(s2v, th, tsh) + (1.f - ALPHA) * fmaf(s2v, sh, sshv);
}

extern "C" void kernel_launch(void* const* d_in, const int* in_sizes, int n_in,
                              void* d_out, int out_size, void* d_ws, size_t ws_size,
                              hipStream_t stream) {
    const float* x  = (const float*)d_in[0];
    const float* w  = (const float*)d_in[1];
    const float* a1 = (const float*)d_in[2];
    const float* a2 = (const float*)d_in[3];
    float* out = (float*)d_out;

    float*  ws   = (float*)d_ws;
    float*  h    = ws;                                   // NR*MO floats
    float2* SHSw = (float2*)(h + (size_t)NR * MO);       // (NR+1)*MO float2
    float2* cSuf = SHSw + (size_t)(NR + 1) * MO;         // (NCH+1)*MO float2
    float*  s1   = (float*)(cSuf + (size_t)(NCH + 1) * MO);
    float*  s2   = s1 + NR;
    float*  s1s  = s2 + NR;
    u64*    keys = (u64*)(s1s + NR);                     // NR u64
    int*    perm = (int*)(keys + NR);
    int*    kidx = perm + NR;
    int*    rank = kidx + NR;
    int*    done = rank + NR;                            // NIR ints

    k_gemm_fused<<<NR / 64, 256, 0, stream>>>(x, w, a1, a2, h, s1, s2, keys, rank, done);
    k_rank<<<dim3(NIR, NJ), 256, 0, stream>>>(keys, s1, rank, done, s1s, perm);
    k_chunk<<<NCH, 256, 0, stream>>>(h, perm, s1s, s2, SHSw, kidx);
    k_scan<<<MO, NCH, 0, stream>>>(SHSw, cSuf);
    k_final<<<(NR * MO) / 256, 256, 0, stream>>>(SHSw, cSuf, s2, kidx, out);
}

// Round 12
// 65.722 us; speedup vs baseline: 1.3046x; 1.3046x over previous
//
#include <hip/hip_runtime.h>
#include <hip/hip_bf16.h>
#include <stdint.h>

#define NR 16384
#define KI 256
#define MO 128
#define ALPHA 0.01f
#define CH 32             // rows per chunk
#define NCH (NR / CH)     // 512 chunks
#define RB 8              // i-keys per thread in k_rank
#define JT 256            // j-keys staged in LDS per block
#define NJ (NR / JT)      // 64 j-chunks
#define NIR (NR / (256 * RB))   // 8 i-ranges

typedef unsigned long long u64;
typedef __attribute__((ext_vector_type(8))) short bf16x8;
typedef __attribute__((ext_vector_type(4))) float f32x4;

// sortable key: monotone float order, index tie-break (rank is a bijection)
static __device__ __forceinline__ u64 sort_key(float f, int j) {
    unsigned u = __float_as_uint(f);
    u ^= ((unsigned)((int)u >> 31)) | 0x80000000u;
    return (((u64)u) << 14) | (unsigned)(j & 0x3FFF);
}

static __device__ __forceinline__ ushort2 cvt2(float a, float b) {
    __hip_bfloat162 r = __float22bfloat162_rn(make_float2(a, b));
    return *reinterpret_cast<ushort2*>(&r);
}

// ---------------- K1: h = x@W^T via bf16 MFMA (R10-proven) + fused s1,s2,keys, rank=0, done=0 ----------------
__global__ __launch_bounds__(256) void k_gemm_fused(const float* __restrict__ x,
                                                    const float* __restrict__ w,
                                                    const float* __restrict__ a1,
                                                    const float* __restrict__ a2,
                                                    float* __restrict__ h,
                                                    float* __restrict__ s1,
                                                    float* __restrict__ s2,
                                                    u64* __restrict__ keys,
                                                    int* __restrict__ rank,
                                                    int* __restrict__ done) {
    __shared__ ushort Abf[64][40];
    __shared__ ushort Bbf[128][40];
    const int t = threadIdx.x;
    const int lane = t & 63;
    const int wv = t >> 6;
    const int rowBase = blockIdx.x * 64;
    const int xr = t >> 2, xc = (t & 3) << 3;
    const int wr = t >> 1, wc = (t & 1) << 4;
    const int fr = lane & 15;
    const int fk = (lane >> 4) << 3;

    if (blockIdx.x == 0 && t < NIR) done[t] = 0;   // re-zero finisher counters every call

    f32x4 acc[8] = {};

    float4 xv0 = *(const float4*)&x[(size_t)(rowBase + xr) * KI + xc];
    float4 xv1 = *(const float4*)&x[(size_t)(rowBase + xr) * KI + xc + 4];
    float4 wv0 = *(const float4*)&w[(size_t)wr * KI + wc];
    float4 wv1 = *(const float4*)&w[(size_t)wr * KI + wc + 4];
    float4 wv2 = *(const float4*)&w[(size_t)wr * KI + wc + 8];
    float4 wv3 = *(const float4*)&w[(size_t)wr * KI + wc + 12];

    for (int ks = 0; ks < KI / 32; ++ks) {
        __syncthreads();
        {
            union { ushort2 u2[4]; bf16x8 v; } ap;
            ap.u2[0] = cvt2(xv0.x, xv0.y); ap.u2[1] = cvt2(xv0.z, xv0.w);
            ap.u2[2] = cvt2(xv1.x, xv1.y); ap.u2[3] = cvt2(xv1.z, xv1.w);
            *(bf16x8*)&Abf[xr][xc] = ap.v;
            union { ushort2 u2[4]; bf16x8 v; } bp0, bp1;
            bp0.u2[0] = cvt2(wv0.x, wv0.y); bp0.u2[1] = cvt2(wv0.z, wv0.w);
            bp0.u2[2] = cvt2(wv1.x, wv1.y); bp0.u2[3] = cvt2(wv1.z, wv1.w);
            bp1.u2[0] = cvt2(wv2.x, wv2.y); bp1.u2[1] = cvt2(wv2.z, wv2.w);
            bp1.u2[2] = cvt2(wv3.x, wv3.y); bp1.u2[3] = cvt2(wv3.z, wv3.w);
            *(bf16x8*)&Bbf[wr][wc] = bp0.v;
            *(bf16x8*)&Bbf[wr][wc + 8] = bp1.v;
        }
        __syncthreads();
        if (ks + 1 < KI / 32) {
            int k0 = (ks + 1) * 32;
            xv0 = *(const float4*)&x[(size_t)(rowBase + xr) * KI + k0 + xc];
            xv1 = *(const float4*)&x[(size_t)(rowBase + xr) * KI + k0 + xc + 4];
            wv0 = *(const float4*)&w[(size_t)wr * KI + k0 + wc];
            wv1 = *(const float4*)&w[(size_t)wr * KI + k0 + wc + 4];
            wv2 = *(const float4*)&w[(size_t)wr * KI + k0 + wc + 8];
            wv3 = *(const float4*)&w[(size_t)wr * KI + k0 + wc + 12];
        }
        bf16x8 af = *(const bf16x8*)&Abf[wv * 16 + fr][fk];
#pragma unroll
        for (int n = 0; n < 8; ++n) {
            bf16x8 bfr = *(const bf16x8*)&Bbf[n * 16 + fr][fk];
            acc[n] = __builtin_amdgcn_mfma_f32_16x16x32_bf16(af, bfr, acc[n], 0, 0, 0);
        }
    }

    const int rq = lane >> 4;
#pragma unroll
    for (int n = 0; n < 8; ++n)
#pragma unroll
        for (int r = 0; r < 4; ++r)
            h[(size_t)(rowBase + wv * 16 + rq * 4 + r) * MO + n * 16 + fr] = acc[n][r];

    float a1v[8], a2v[8];
#pragma unroll
    for (int n = 0; n < 8; ++n) { a1v[n] = a1[n * 16 + fr]; a2v[n] = a2[n * 16 + fr]; }
#pragma unroll
    for (int r = 0; r < 4; ++r) {
        float p1 = 0.f, p2 = 0.f;
#pragma unroll
        for (int n = 0; n < 8; ++n) {
            p1 = fmaf(acc[n][r], a1v[n], p1);
            p2 = fmaf(acc[n][r], a2v[n], p2);
        }
#pragma unroll
        for (int off = 8; off; off >>= 1) {
            p1 += __shfl_xor(p1, off, 64);
            p2 += __shfl_xor(p2, off, 64);
        }
        if (fr == 0) {
            int row = rowBase + wv * 16 + rq * 4 + r;
            s1[row] = p1;
            s2[row] = p2;
            keys[row] = sort_key(p1, row);
            rank[row] = 0;
        }
    }
}

// ---------------- K2: rank counts + last-finisher scatter (wave-local waitcnt, NO device fence) ----------------
__global__ __launch_bounds__(256) void k_rank(const u64* __restrict__ keys,
                                              const float* __restrict__ s1,
                                              int* __restrict__ rank,
                                              int* __restrict__ done,
                                              float* __restrict__ s1s,
                                              int* __restrict__ perm) {
    __shared__ u64 sk[JT];
    __shared__ int lastFlag;
    const int t = threadIdx.x;
    const int ibase = blockIdx.x * (256 * RB);
    const int jbase = blockIdx.y * JT;
    if (t == 0) lastFlag = 0;
    sk[t] = keys[jbase + t];
    u64 ki[RB];
#pragma unroll
    for (int k = 0; k < RB; ++k) ki[k] = keys[ibase + k * 256 + t];
    int cnt[RB] = {};
    __syncthreads();
#pragma unroll 4
    for (int jj = 0; jj < JT; ++jj) {
        u64 kj = sk[jj];                 // uniform addr -> LDS broadcast, conflict-free
#pragma unroll
        for (int k = 0; k < RB; ++k)
            cnt[k] += (kj < ki[k]) ? 1 : 0;
    }
#pragma unroll
    for (int k = 0; k < RB; ++k)
        atomicAdd(&rank[ibase + k * 256 + t], cnt[k]);   // device-coherent, deterministic sum

    // wave-local drain: this wave's atomics have reached the coherence point.
    // (No __threadfence — that triggers an L2 writeback storm on gfx950; R11 measured +43 µs.)
    asm volatile("s_waitcnt vmcnt(0)" ::: "memory");
    __syncthreads();
    if (t == 0) {
        if (atomicAdd(&done[blockIdx.x], 1) == NJ - 1) lastFlag = 1;
    }
    __syncthreads();
    if (lastFlag) {
        // all 64 j-slices for this i-range complete; ranks final. Scatter inline.
#pragma unroll
        for (int k = 0; k < RB; ++k) {
            int i = ibase + k * 256 + t;
            int r = atomicAdd(&rank[i], 0);   // coherent read of final rank
            s1s[r] = s1[i];
            perm[r] = i;
        }
    }
}

// ---------------- K3: within-chunk suffix + kidx searches on idle half-wave (R9-proven) ----------------
__global__ __launch_bounds__(256) void k_chunk(const float* __restrict__ h,
                                               const int* __restrict__ perm,
                                               const float* __restrict__ s1s,
                                               const float* __restrict__ s2,
                                               float2* __restrict__ SHSw,
                                               int* __restrict__ kidx) {
    __shared__ int pi[CH];
    __shared__ float ss[CH];
    __shared__ float rH[128], rS[128];
    const int t = threadIdx.x, c = t & 127, g = t >> 7, q = blockIdx.x;
    if (t < CH) { pi[t] = perm[q * CH + t]; ss[t] = s1s[q * CH + t]; }
    __syncthreads();
    float v[16];
#pragma unroll
    for (int m = 0; m < 16; ++m)
        v[m] = h[(size_t)pi[g * 16 + m] * MO + c];
    if (g == 1) {
        float runH = 0.f, runS = 0.f;
#pragma unroll
        for (int m = 15; m >= 0; --m) {
            runH += v[m];
            runS = fmaf(ss[16 + m], v[m], runS);
            SHSw[(size_t)(q * CH + 16 + m) * MO + c] = make_float2(runH, runS);
        }
        rH[c] = runH; rS[c] = runS;
    } else if (t < CH) {
        int i = q * CH + t;
        float tv = -s2[i];
        int lo = 0, hi = NR;
        while (lo < hi) {
            int mid = (lo + hi) >> 1;
            if (s1s[mid] < tv) lo = mid + 1; else hi = mid;
        }
        kidx[i] = lo;
    }
    __syncthreads();
    if (g == 0) {
        float runH = rH[c], runS = rS[c];
#pragma unroll
        for (int m = 15; m >= 0; --m) {
            runH += v[m];
            runS = fmaf(ss[m], v[m], runS);
            SHSw[(size_t)(q * CH + m) * MO + c] = make_float2(runH, runS);
        }
    }
    if (q == NCH - 1 && t < 128) SHSw[(size_t)NR * MO + t] = make_float2(0.f, 0.f);
}

// ---------------- K4: exclusive suffix over chunk sums (R9-proven) ----------------
__global__ __launch_bounds__(512) void k_scan(const float2* __restrict__ SHSw,
                                              float2* __restrict__ cSuf) {
    __shared__ float bufH[NCH], bufS[NCH];
    const int c = blockIdx.x, q = threadIdx.x;
    float2 hs = SHSw[(size_t)(q * CH) * MO + c];
    bufH[q] = hs.x; bufS[q] = hs.y;
    __syncthreads();
#pragma unroll
    for (int off = 1; off < NCH; off <<= 1) {
        float ah = 0.f, as = 0.f;
        if (q + off < NCH) { ah = bufH[q + off]; as = bufS[q + off]; }
        __syncthreads();
        bufH[q] += ah; bufS[q] += as;
        __syncthreads();
    }
    cSuf[q * MO + c] = make_float2(bufH[q] - hs.x, bufS[q] - hs.y);
    if (q == 0) cSuf[(size_t)NCH * MO + c] = make_float2(0.f, 0.f);
}

// ---------------- K5: out[i][c]; SH = SHSw[k]+cSuf[k>>5] (R9-proven) ----------------
__global__ __launch_bounds__(256) void k_final(const float2* __restrict__ SHSw,
                                               const float2* __restrict__ cSuf,
                                               const float* __restrict__ s2,
                                               const int* __restrict__ kidx,
                                               float* __restrict__ out) {
    int idx = blockIdx.x * 256 + threadIdx.x;
    int i = idx >> 7, c = idx & 127;
    float s2v = s2[i];
    int k = kidx[i];
    float2 w0 = SHSw[c];
    float2 c0 = cSuf[c];
    float2 wk = SHSw[(size_t)k * MO + c];
    float2 ck = cSuf[(size_t)(k >> 5) * MO + c];
    float th = w0.x + c0.x, tsh = w0.y + c0.y;
    float sh = wk.x + ck.x, sshv = wk.y + ck.y;
    out[idx] = ALPHA * fmaf(s2v, th, tsh) + (1.f - ALPHA) * fmaf(s2v, sh, sshv);
}

extern "C" void kernel_launch(void* const* d_in, const int* in_sizes, int n_in,
                              void* d_out, int out_size, void* d_ws, size_t ws_size,
                              hipStream_t stream) {
    const float* x  = (const float*)d_in[0];
    const float* w  = (const float*)d_in[1];
    const float* a1 = (const float*)d_in[2];
    const float* a2 = (const float*)d_in[3];
    float* out = (float*)d_out;

    float*  ws   = (float*)d_ws;
    float*  h    = ws;                                   // NR*MO floats
    float2* SHSw = (float2*)(h + (size_t)NR * MO);       // (NR+1)*MO float2
    float2* cSuf = SHSw + (size_t)(NR + 1) * MO;         // (NCH+1)*MO float2
    float*  s1   = (float*)(cSuf + (size_t)(NCH + 1) * MO);
    float*  s2   = s1 + NR;
    float*  s1s  = s2 + NR;
    u64*    keys = (u64*)(s1s + NR);                     // NR u64
    int*    perm = (int*)(keys + NR);
    int*    kidx = perm + NR;
    int*    rank = kidx + NR;
    int*    done = rank + NR;                            // NIR ints

    k_gemm_fused<<<NR / 64, 256, 0, stream>>>(x, w, a1, a2, h, s1, s2, keys, rank, done);
    k_rank<<<dim3(NIR, NJ), 256, 0, stream>>>(keys, s1, rank, done, s1s, perm);
    k_chunk<<<NCH, 256, 0, stream>>>(h, perm, s1s, s2, SHSw, kidx);
    k_scan<<<MO, NCH, 0, stream>>>(SHSw, cSuf);
    k_final<<<(NR * MO) / 256, 256, 0, stream>>>(SHSw, cSuf, s2, kidx, out);
}

// Round 13
// 56.960 us; speedup vs baseline: 1.5053x; 1.1538x over previous
//
#include <hip/hip_runtime.h>
#include <hip/hip_bf16.h>
#include <stdint.h>

#define NR 16384
#define KI 256
#define MO 128
#define ALPHA 0.01f
#define CH 32             // rows per chunk
#define NCH (NR / CH)     // 512 chunks
#define RB 8              // i-keys per thread in k_rank
#define JT 256            // j-keys staged in LDS per block
#define NJ (NR / JT)      // 64 j-chunks

typedef unsigned long long u64;
typedef __attribute__((ext_vector_type(8))) short bf16x8;
typedef __attribute__((ext_vector_type(4))) float f32x4;

// sortable key: monotone float order, index tie-break (rank is a bijection)
static __device__ __forceinline__ u64 sort_key(float f, int j) {
    unsigned u = __float_as_uint(f);
    u ^= ((unsigned)((int)u >> 31)) | 0x80000000u;
    return (((u64)u) << 14) | (unsigned)(j & 0x3FFF);
}

static __device__ __forceinline__ ushort2 cvt2(float a, float b) {
    __hip_bfloat162 r = __float22bfloat162_rn(make_float2(a, b));
    return *reinterpret_cast<ushort2*>(&r);
}

// bf16 scalar pack/unpack (RNE; bit-exact unpack)
static __device__ __forceinline__ unsigned f2b(float f) {
    unsigned x = __float_as_uint(f);
    return (x + 0x7fffu + ((x >> 16) & 1u)) >> 16;
}
static __device__ __forceinline__ float b2f(unsigned u) {
    return __uint_as_float(u << 16);
}
static __device__ __forceinline__ unsigned pk(float hv, float sv) {
    return f2b(hv) | (f2b(sv) << 16);
}

// ---------------- K1: h(bf16) = x@W^T via bf16 MFMA + fused s1,s2,keys, rank=0 (R10 + bf16 h-store) ----------------
__global__ __launch_bounds__(256) void k_gemm_fused(const float* __restrict__ x,
                                                    const float* __restrict__ w,
                                                    const float* __restrict__ a1,
                                                    const float* __restrict__ a2,
                                                    ushort* __restrict__ hb,
                                                    float* __restrict__ s1,
                                                    float* __restrict__ s2,
                                                    u64* __restrict__ keys,
                                                    int* __restrict__ rank) {
    __shared__ ushort Abf[64][40];
    __shared__ ushort Bbf[128][40];
    const int t = threadIdx.x;
    const int lane = t & 63;
    const int wv = t >> 6;
    const int rowBase = blockIdx.x * 64;
    const int xr = t >> 2, xc = (t & 3) << 3;
    const int wr = t >> 1, wc = (t & 1) << 4;
    const int fr = lane & 15;
    const int fk = (lane >> 4) << 3;

    f32x4 acc[8] = {};

    float4 xv0 = *(const float4*)&x[(size_t)(rowBase + xr) * KI + xc];
    float4 xv1 = *(const float4*)&x[(size_t)(rowBase + xr) * KI + xc + 4];
    float4 wv0 = *(const float4*)&w[(size_t)wr * KI + wc];
    float4 wv1 = *(const float4*)&w[(size_t)wr * KI + wc + 4];
    float4 wv2 = *(const float4*)&w[(size_t)wr * KI + wc + 8];
    float4 wv3 = *(const float4*)&w[(size_t)wr * KI + wc + 12];

    for (int ks = 0; ks < KI / 32; ++ks) {
        __syncthreads();
        {
            union { ushort2 u2[4]; bf16x8 v; } ap;
            ap.u2[0] = cvt2(xv0.x, xv0.y); ap.u2[1] = cvt2(xv0.z, xv0.w);
            ap.u2[2] = cvt2(xv1.x, xv1.y); ap.u2[3] = cvt2(xv1.z, xv1.w);
            *(bf16x8*)&Abf[xr][xc] = ap.v;
            union { ushort2 u2[4]; bf16x8 v; } bp0, bp1;
            bp0.u2[0] = cvt2(wv0.x, wv0.y); bp0.u2[1] = cvt2(wv0.z, wv0.w);
            bp0.u2[2] = cvt2(wv1.x, wv1.y); bp0.u2[3] = cvt2(wv1.z, wv1.w);
            bp1.u2[0] = cvt2(wv2.x, wv2.y); bp1.u2[1] = cvt2(wv2.z, wv2.w);
            bp1.u2[2] = cvt2(wv3.x, wv3.y); bp1.u2[3] = cvt2(wv3.z, wv3.w);
            *(bf16x8*)&Bbf[wr][wc] = bp0.v;
            *(bf16x8*)&Bbf[wr][wc + 8] = bp1.v;
        }
        __syncthreads();
        if (ks + 1 < KI / 32) {
            int k0 = (ks + 1) * 32;
            xv0 = *(const float4*)&x[(size_t)(rowBase + xr) * KI + k0 + xc];
            xv1 = *(const float4*)&x[(size_t)(rowBase + xr) * KI + k0 + xc + 4];
            wv0 = *(const float4*)&w[(size_t)wr * KI + k0 + wc];
            wv1 = *(const float4*)&w[(size_t)wr * KI + k0 + wc + 4];
            wv2 = *(const float4*)&w[(size_t)wr * KI + k0 + wc + 8];
            wv3 = *(const float4*)&w[(size_t)wr * KI + k0 + wc + 12];
        }
        bf16x8 af = *(const bf16x8*)&Abf[wv * 16 + fr][fk];
#pragma unroll
        for (int n = 0; n < 8; ++n) {
            bf16x8 bfr = *(const bf16x8*)&Bbf[n * 16 + fr][fk];
            acc[n] = __builtin_amdgcn_mfma_f32_16x16x32_bf16(af, bfr, acc[n], 0, 0, 0);
        }
    }

    // epilogue: bf16 h-store. C/D: col = lane&15, row = (lane>>4)*4 + reg
    const int rq = lane >> 4;
#pragma unroll
    for (int n = 0; n < 8; ++n)
#pragma unroll
        for (int r = 0; r < 4; ++r)
            hb[(size_t)(rowBase + wv * 16 + rq * 4 + r) * MO + n * 16 + fr] = (ushort)f2b(acc[n][r]);

    float a1v[8], a2v[8];
#pragma unroll
    for (int n = 0; n < 8; ++n) { a1v[n] = a1[n * 16 + fr]; a2v[n] = a2[n * 16 + fr]; }
#pragma unroll
    for (int r = 0; r < 4; ++r) {
        float p1 = 0.f, p2 = 0.f;
#pragma unroll
        for (int n = 0; n < 8; ++n) {
            p1 = fmaf(acc[n][r], a1v[n], p1);
            p2 = fmaf(acc[n][r], a2v[n], p2);
        }
#pragma unroll
        for (int off = 8; off; off >>= 1) {
            p1 += __shfl_xor(p1, off, 64);
            p2 += __shfl_xor(p2, off, 64);
        }
        if (fr == 0) {
            int row = rowBase + wv * 16 + rq * 4 + r;
            s1[row] = p1;
            s2[row] = p2;
            keys[row] = sort_key(p1, row);
            rank[row] = 0;
        }
    }
}

// ---------------- K2: rank counts — LDS-broadcast j-keys, 8 i-keys/thread, int atomicAdd (R10-proven) ----------------
__global__ __launch_bounds__(256) void k_rank(const u64* __restrict__ keys,
                                              int* __restrict__ rank) {
    __shared__ u64 sk[JT];
    const int t = threadIdx.x;
    const int ibase = blockIdx.x * (256 * RB);
    const int jbase = blockIdx.y * JT;
    sk[t] = keys[jbase + t];
    u64 ki[RB];
#pragma unroll
    for (int k = 0; k < RB; ++k) ki[k] = keys[ibase + k * 256 + t];
    int cnt[RB] = {};
    __syncthreads();
#pragma unroll 4
    for (int jj = 0; jj < JT; ++jj) {
        u64 kj = sk[jj];                 // uniform addr -> LDS broadcast, conflict-free
#pragma unroll
        for (int k = 0; k < RB; ++k)
            cnt[k] += (kj < ki[k]) ? 1 : 0;
    }
#pragma unroll
    for (int k = 0; k < RB; ++k)
        atomicAdd(&rank[ibase + k * 256 + t], cnt[k]);   // int: deterministic
}

// ---------------- K3: scatter into sorted order (R10-proven) ----------------
__global__ __launch_bounds__(256) void k_scatter(const float* __restrict__ s1,
                                                 const int* __restrict__ rank,
                                                 float* __restrict__ s1s,
                                                 int* __restrict__ perm) {
    int i = blockIdx.x * 256 + threadIdx.x;
    int r = rank[i];
    s1s[r] = s1[i];
    perm[r] = i;
}

// ---------------- K4: within-chunk suffix (packed bf16x2 SHS) + kidx on idle half-wave ----------------
__global__ __launch_bounds__(256) void k_chunk(const ushort* __restrict__ hb,
                                               const int* __restrict__ perm,
                                               const float* __restrict__ s1s,
                                               const float* __restrict__ s2,
                                               unsigned* __restrict__ SHS,
                                               int* __restrict__ kidx) {
    __shared__ int pi[CH];
    __shared__ float ss[CH];
    __shared__ float rH[128], rS[128];
    const int t = threadIdx.x, c = t & 127, g = t >> 7, q = blockIdx.x;
    if (t < CH) { pi[t] = perm[q * CH + t]; ss[t] = s1s[q * CH + t]; }
    __syncthreads();
    float v[16];
#pragma unroll
    for (int m = 0; m < 16; ++m)
        v[m] = b2f(hb[(size_t)pi[g * 16 + m] * MO + c]);
    if (g == 1) {
        float runH = 0.f, runS = 0.f;
#pragma unroll
        for (int m = 15; m >= 0; --m) {
            runH += v[m];
            runS = fmaf(ss[16 + m], v[m], runS);
            SHS[(size_t)(q * CH + 16 + m) * MO + c] = pk(runH, runS);
        }
        rH[c] = runH; rS[c] = runS;
    } else if (t < CH) {
        int i = q * CH + t;
        float tv = -s2[i];
        int lo = 0, hi = NR;
        while (lo < hi) {
            int mid = (lo + hi) >> 1;
            if (s1s[mid] < tv) lo = mid + 1; else hi = mid;
        }
        kidx[i] = lo;
    }
    __syncthreads();
    if (g == 0) {
        float runH = rH[c], runS = rS[c];
#pragma unroll
        for (int m = 15; m >= 0; --m) {
            runH += v[m];
            runS = fmaf(ss[m], v[m], runS);
            SHS[(size_t)(q * CH + m) * MO + c] = pk(runH, runS);
        }
    }
    if (q == NCH - 1 && t < 128) SHS[(size_t)NR * MO + t] = 0u;
}

// ---------------- K5: exclusive suffix over chunk sums (reads packed heads; fp32 scan) ----------------
__global__ __launch_bounds__(512) void k_scan(const unsigned* __restrict__ SHS,
                                              float2* __restrict__ cSuf) {
    __shared__ float bufH[NCH], bufS[NCH];
    const int c = blockIdx.x, q = threadIdx.x;
    unsigned hu = SHS[(size_t)(q * CH) * MO + c];   // inclusive within-chunk suffix at head = chunk sum
    float vh = b2f(hu & 0xffffu), vs = b2f(hu >> 16);
    bufH[q] = vh; bufS[q] = vs;
    __syncthreads();
#pragma unroll
    for (int off = 1; off < NCH; off <<= 1) {
        float ah = 0.f, as = 0.f;
        if (q + off < NCH) { ah = bufH[q + off]; as = bufS[q + off]; }
        __syncthreads();
        bufH[q] += ah; bufS[q] += as;
        __syncthreads();
    }
    cSuf[q * MO + c] = make_float2(bufH[q] - vh, bufS[q] - vs);   // chunks > q
    if (q == 0) cSuf[(size_t)NCH * MO + c] = make_float2(0.f, 0.f);
}

// ---------------- K6: out[i][c]; SH = unpack(SHS[k]) + cSuf[k>>5] ----------------
__global__ __launch_bounds__(256) void k_final(const unsigned* __restrict__ SHS,
                                               const float2* __restrict__ cSuf,
                                               const float* __restrict__ s2,
                                               const int* __restrict__ kidx,
                                               float* __restrict__ out) {
    int idx = blockIdx.x * 256 + threadIdx.x;
    int i = idx >> 7, c = idx & 127;
    float s2v = s2[i];
    int k = kidx[i];
    unsigned w0u = SHS[c];
    float2 c0 = cSuf[c];
    unsigned wku = SHS[(size_t)k * MO + c];
    float2 ck = cSuf[(size_t)(k >> 5) * MO + c];    // CH = 32
    float th  = b2f(w0u & 0xffffu) + c0.x, tsh  = b2f(w0u >> 16) + c0.y;
    float sh  = b2f(wku & 0xffffu) + ck.x, sshv = b2f(wku >> 16) + ck.y;
    out[idx] = ALPHA * fmaf(s2v, th, tsh) + (1.f - ALPHA) * fmaf(s2v, sh, sshv);
}

extern "C" void kernel_launch(void* const* d_in, const int* in_sizes, int n_in,
                              void* d_out, int out_size, void* d_ws, size_t ws_size,
                              hipStream_t stream) {
    const float* x  = (const float*)d_in[0];
    const float* w  = (const float*)d_in[1];
    const float* a1 = (const float*)d_in[2];
    const float* a2 = (const float*)d_in[3];
    float* out = (float*)d_out;

    char* ws = (char*)d_ws;
    ushort*   hb   = (ushort*)ws;                                   // NR*MO bf16 (4 MB)
    unsigned* SHS  = (unsigned*)(ws + (size_t)NR * MO * 2);         // (NR+1)*MO packed bf16x2 (8.4 MB)
    float2*   cSuf = (float2*)((char*)SHS + (size_t)(NR + 1) * MO * 4);  // (NCH+1)*MO float2
    float*    s1   = (float*)((char*)cSuf + (size_t)(NCH + 1) * MO * 8);
    float*    s2   = s1 + NR;
    float*    s1s  = s2 + NR;
    u64*      keys = (u64*)(s1s + NR);                              // NR u64 (8B-aligned by construction)
    int*      perm = (int*)(keys + NR);
    int*      kidx = perm + NR;
    int*      rank = kidx + NR;

    k_gemm_fused<<<NR / 64, 256, 0, stream>>>(x, w, a1, a2, hb, s1, s2, keys, rank);
    k_rank<<<dim3(NR / (256 * RB), NJ), 256, 0, stream>>>(keys, rank);
    k_scatter<<<NR / 256, 256, 0, stream>>>(s1, rank, s1s, perm);
    k_chunk<<<NCH, 256, 0, stream>>>(hb, perm, s1s, s2, SHS, kidx);
    k_scan<<<MO, NCH, 0, stream>>>(SHS, cSuf);
    k_final<<<(NR * MO) / 256, 256, 0, stream>>>(SHS, cSuf, s2, kidx, out);
}